// Round 6
// baseline (5008.875 us; speedup 1.0000x reference)
//
#include <hip/hip_runtime.h>

#define S_LEN 256
#define B_SZ 64
#define I_SZ 512
#define H_SZ 1024
#define NBLK 256

typedef __bf16 bf16x8 __attribute__((ext_vector_type(8)));
typedef float f32x4 __attribute__((ext_vector_type(4)));
typedef unsigned long long u64;

__device__ __forceinline__ float sigmoidf_(float x){ return 1.f/(1.f + expf(-x)); }

// ---- device-coherent (MALL) access helpers: bypass L1+L2, no fences ----
__device__ __forceinline__ u64 ld_cc64(const u64* p){
  return __hip_atomic_load(p, __ATOMIC_RELAXED, __HIP_MEMORY_SCOPE_AGENT);
}
__device__ __forceinline__ void st_cc16(__bf16* p, __bf16 v){
  unsigned short b = __builtin_bit_cast(unsigned short, v);
  __hip_atomic_store((unsigned short*)p, b, __ATOMIC_RELAXED, __HIP_MEMORY_SCOPE_AGENT);
}
__device__ __forceinline__ void st_cc32(float* p, float v){
  __hip_atomic_store(p, v, __ATOMIC_RELAXED, __HIP_MEMORY_SCOPE_AGENT);
}
__device__ __forceinline__ float ld_cc32f(const float* p){
  return __hip_atomic_load(p, __ATOMIC_RELAXED, __HIP_MEMORY_SCOPE_AGENT);
}

// ---------------- prep kernels ----------------

__global__ __launch_bounds__(64) void pack_w4_k(const float* __restrict__ Wf, const float* __restrict__ Wi,
                                                const float* __restrict__ Wu, const float* __restrict__ Wo,
                                                __bf16* __restrict__ W4p){
  int blk = blockIdx.x;           // nt16*48 + kb
  int nt = blk / 48, kb = blk % 48;
  int l = threadIdx.x;
  int n = nt*16 + (l & 15);
  int g = n >> 10, h = n & 1023;
  const float* W = (g==0)?Wf:((g==1)?Wi:((g==2)?Wu:Wo));
  int k0 = kb*32 + ((l>>4)<<3);
  __bf16 tmp[8];
#pragma unroll
  for (int j=0;j<8;j++) tmp[j] = (__bf16)W[(size_t)(k0+j)*H_SZ + h];
  *reinterpret_cast<bf16x8*>(W4p + ((size_t)blk*64 + l)*8) = *reinterpret_cast<bf16x8*>(tmp);
}

__global__ __launch_bounds__(64) void pack_wc_k(const float* __restrict__ Wc, __bf16* __restrict__ Wcp){
  int blk = blockIdx.x;           // nt16*32 + kb
  int nt = blk / 32, kb = blk % 32;
  int l = threadIdx.x;
  int n = nt*16 + (l & 15);
  int k0 = kb*32 + ((l>>4)<<3);
  __bf16 tmp[8];
#pragma unroll
  for (int j=0;j<8;j++) tmp[j] = (__bf16)Wc[(size_t)(k0+j)*H_SZ + n];
  *reinterpret_cast<bf16x8*>(Wcp + ((size_t)blk*64 + l)*8) = *reinterpret_cast<bf16x8*>(tmp);
}

__global__ void cast_x_k(const float* __restrict__ x, __bf16* __restrict__ xb, int n){
  int stride = gridDim.x * blockDim.x * 4;
  for (int i = (blockIdx.x*blockDim.x + threadIdx.x)*4; i < n; i += stride){
    float4 v = *reinterpret_cast<const float4*>(x + i);
    __bf16 o[4] = {(__bf16)v.x, (__bf16)v.y, (__bf16)v.z, (__bf16)v.w};
    *reinterpret_cast<uint2*>(xb + i) = *reinterpret_cast<const uint2*>(o);
  }
}

__global__ void init_h_k(__bf16* __restrict__ hxb){
  int i = blockIdx.x*blockDim.x + threadIdx.x;   // 65536 threads
  hxb[i] = (__bf16)0.f;
}

// ---------------- global flag-array grid barrier (round-4 verbatim) ----------------
__device__ __forceinline__ void flag_bar(unsigned* flags, unsigned target){
  asm volatile("" ::: "memory");
  __syncthreads();
  if (threadIdx.x == 0)
    __hip_atomic_store(&flags[blockIdx.x], target, __ATOMIC_RELAXED, __HIP_MEMORY_SCOPE_AGENT);
  if (threadIdx.x < 64){
    const u64* f = (const u64*)flags;
    int i0 = (int)threadIdx.x * 2;
    for(;;){
      u64 a = __hip_atomic_load(f+i0,   __ATOMIC_RELAXED, __HIP_MEMORY_SCOPE_AGENT);
      u64 b = __hip_atomic_load(f+i0+1, __ATOMIC_RELAXED, __HIP_MEMORY_SCOPE_AGENT);
      bool ok = ((unsigned)a >= target) && ((unsigned)(a>>32) >= target)
             && ((unsigned)b >= target) && ((unsigned)(b>>32) >= target);
      if (__all(ok)) break;
      __builtin_amdgcn_s_sleep(1);
    }
  }
  __syncthreads();
}

// ---------------- persistent kernel: all 256 steps ----------------
// Round-4 structure; only the LDS staging layouts changed to identity
// fragment-order (bank-conflict-free ds_read_b128).
// Phase 1: block (mt1, nt64): rows mt1*16..+16, cols nt64*64..+64; wave = 16-col
//          tile; W4 frags in 192 VGPR; hx staged frag-order (32 KB).
// Phase 2: block (mt2, ht): rows mt2*8..+8, h-cols ht*32..+32; wave = gate;
//          act staged frag-order per-gate 16 KB tiles (8 valid rows, lanes
//          8..15 broadcast-read rows 0..7 -> D rows 8..15 dup, discarded).

__global__ __launch_bounds__(256, 1) void qlstm_persist_k(
    const __bf16* __restrict__ xb,
    __bf16* hxb,
    const __bf16* __restrict__ W4p, const __bf16* __restrict__ Wcp,
    const float* __restrict__ bfv, const float* __restrict__ biv,
    const float* __restrict__ buv, const float* __restrict__ bov,
    const float* __restrict__ pf, const float* __restrict__ piq,
    const float* __restrict__ pu, const float* __restrict__ po,
    const float* __restrict__ WcLast, const float* __restrict__ bc,
    __bf16* act, float* zact,
    float* __restrict__ out,
    unsigned* flags)
{
  __shared__ __align__(16) __bf16 ldsWc[2*32*64*8];   // 64 KiB, persistent
  __shared__ __align__(16) char ldsStage[65536];      // 64 KiB (p1: 32K, p2: 64K)
  __shared__ float gx[4][8][32];
  __shared__ float pre4[16][4];

  const int tid = threadIdx.x;
  const int bid = blockIdx.x;
  const int wave = tid >> 6;
  const int l = tid & 63;
  const int col = l & 15;
  const int kq = l >> 4;
  const int ksub8 = kq * 8;

  // ---- phase-1 ids ----
  const int mt1 = bid >> 6;
  const int nt64 = bid & 63;
  const int nt16 = nt64*4 + wave;
  const int g1 = nt16 >> 6;
  const int h1 = (nt16*16 + col) & 1023;

  // ---- phase-2 ids ----
  const int mt2 = bid >> 5;                // 0..7 -> 8-row batch tile
  const int ht  = bid & 31;                // 32 h-cols
  const int r2 = tid >> 5;
  const int c2 = tid & 31;
  const int b2 = mt2*8 + r2;
  const int h2 = ht*32 + c2;
  // phase-2 staging lane constants (identity class mapping)
  const int cls = l & 31;                  // = kq8*8 + r8
  const int r8  = cls & 7;
  const int kq8 = cls >> 3;
  const int jh  = l >> 5;
  const int aoff = (kq*8 + (l & 7))*16;    // frag read: lanes l, l+8 same addr

  // ---- W4 fragments -> registers (48 x bf16x8 = 192 VGPR) ----
  bf16x8 wfrag[48];
  {
    const bf16x8* src = (const bf16x8*)(W4p + ((size_t)nt16*48*64 + (size_t)l)*8);
#pragma unroll
    for (int kb=0;kb<48;kb++) wfrag[kb] = src[(size_t)kb*64];
  }
  // ---- Wc frags (nt16 = ht*2, ht*2+1) -> LDS, persistent ----
  {
    const u64* src = (const u64*)(Wcp + (size_t)(ht*2)*32*64*8);
    u64* dst = (u64*)ldsWc;
    for (int i = tid; i < 8192; i += 256) dst[i] = src[i];
  }

  const float* bptr = (g1==0)?bfv:((g1==1)?biv:((g1==2)?buv:bov));
  const float bias1 = bptr[h1];
  const bool isU1 = (g1==2);
  const bool isQb = ((nt64 & 15) == 0);
  const int gq = nt64 >> 4;
  float pq0=0.f,pq1=0.f,pq2=0.f,pq3=0.f;
  if (isQb && wave==0){
    const float* pq = (gq==0)?pf:((gq==1)?piq:((gq==2)?pu:po));
    pq0=pq[0]; pq1=pq[1]; pq2=pq[2]; pq3=pq[3];
  }

  const float wl2 = WcLast[h2];
  const float bc2 = bc[h2];
  float creg = 0.f;

  __syncthreads();   // Wc staged

  const size_t SBH = (size_t)S_LEN*B_SZ*H_SZ;

  for (int s = 0; s < S_LEN; ++s){
    // ================= phase 1: pre + activations + qgate =================
    {
      // hx loads (coherent, frag-order identity): chunk j = wave + 4i
      u64 tlo[8], thi[8];
#pragma unroll
      for (int i=0;i<8;i++){
        int j = wave + 4*i;
        const u64* p = (const u64*)(hxb + (size_t)(mt1*16 + col)*H_SZ + ksub8 + 32*j);
        tlo[i] = ld_cc64(p); thi[i] = ld_cc64(p+1);
      }

      // x part overlaps the MALL latency
      const __bf16* xrow = xb + ((size_t)s*B_SZ + (size_t)(mt1*16 + col))*I_SZ + ksub8;
      f32x4 acc[4] = {{0,0,0,0},{0,0,0,0},{0,0,0,0},{0,0,0,0}};
#pragma unroll
      for (int kb=0;kb<16;kb++){
        bf16x8 a = *reinterpret_cast<const bf16x8*>(xrow + kb*32);
        acc[kb&3] = __builtin_amdgcn_mfma_f32_16x16x32_bf16(a, wfrag[kb], acc[kb&3], 0,0,0);
      }

#pragma unroll
      for (int i=0;i<8;i++){
        int j = wave + 4*i;
        ulonglong2 v; v.x = tlo[i]; v.y = thi[i];
        *reinterpret_cast<ulonglong2*>(ldsStage + j*1024 + l*16) = v;
      }
      __syncthreads();

#pragma unroll
      for (int kb=16;kb<48;kb++){
        bf16x8 a = *reinterpret_cast<const bf16x8*>(ldsStage + (kb-16)*1024 + l*16);
        acc[kb&3] = __builtin_amdgcn_mfma_f32_16x16x32_bf16(a, wfrag[kb], acc[kb&3], 0,0,0);
      }
      f32x4 r = (acc[0]+acc[1])+(acc[2]+acc[3]);
      float pr[4];
#pragma unroll
      for (int rr=0;rr<4;rr++){
        int brow = mt1*16 + (kq<<2) + rr;
        float p = r[rr] + bias1;
        pr[rr] = p;
        float a = isU1 ? tanhf(p) : sigmoidf_(p);
        st_cc16(&act[((size_t)g1*B_SZ + brow)*H_SZ + h1], (__bf16)a);
      }
      if (isQb && wave==0){
        if (col < 4){
#pragma unroll
          for (int rr=0;rr<4;rr++) pre4[(kq<<2)+rr][col] = pr[rr];
        }
        if (l < 16){
          float th = pre4[l][0]*pq0 + pre4[l][1]*pq1 + pre4[l][2]*pq2 + pre4[l][3]*pq3;
          float z = cosf(2.f*th);
          st_cc32(&zact[gq*B_SZ + mt1*16 + l], (gq==2) ? z : sigmoidf_(z));
        }
      }
    }

    flag_bar(flags, (unsigned)(2*s+1));

    // ================= phase 2: comb + cell update =================
    {
      // stage own gate's 8 rows into frag-order tile (identity class map)
      const __bf16* abase = act + (size_t)(wave*B_SZ + mt2*8 + r8)*H_SZ + kq8*8;
      u64 alo[16], ahi[16];
#pragma unroll
      for (int i=0;i<16;i++){
        int j = i*2 + jh;
        const u64* p = (const u64*)(abase + 32*j);
        alo[i] = ld_cc64(p); ahi[i] = ld_cc64(p+1);
      }
      float zf = ld_cc32f(&zact[      b2]);
      float zi = ld_cc32f(&zact[ 64 + b2]);
      float zu = ld_cc32f(&zact[128 + b2]);
      float zo = ld_cc32f(&zact[192 + b2]);
#pragma unroll
      for (int i=0;i<16;i++){
        int j = i*2 + jh;
        ulonglong2 v; v.x = alo[i]; v.y = ahi[i];
        *reinterpret_cast<ulonglong2*>(ldsStage + wave*16384 + j*512 + cls*16) = v;
      }
      __syncthreads();

      // wave = gate: comb over K=1024 for 8 rows x 32 h-cols
      const char* Ab = ldsStage + wave*16384;
      const bf16x8* bf0 = (const bf16x8*)ldsWc + l;
      const bf16x8* bf1 = (const bf16x8*)ldsWc + 32*64 + l;
      f32x4 acc2[4] = {{0,0,0,0},{0,0,0,0},{0,0,0,0},{0,0,0,0}};
#pragma unroll
      for (int kb=0;kb<32;kb++){
        bf16x8 a = *reinterpret_cast<const bf16x8*>(Ab + kb*512 + aoff);
        acc2[kb&1]     = __builtin_amdgcn_mfma_f32_16x16x32_bf16(a, bf0[(size_t)kb*64], acc2[kb&1], 0,0,0);
        acc2[2+(kb&1)] = __builtin_amdgcn_mfma_f32_16x16x32_bf16(a, bf1[(size_t)kb*64], acc2[2+(kb&1)], 0,0,0);
      }
      f32x4 rA = acc2[0]+acc2[1];
      f32x4 rB = acc2[2]+acc2[3];
#pragma unroll
      for (int rr=0;rr<4;rr++){
        int row = (kq<<2) + rr;            // rows 8..15 are duplicates, discard
        if (row < 8){
          gx[wave][row][col]      = rA[rr];
          gx[wave][row][16 + col] = rB[rr];
        }
      }
      __syncthreads();

      float fg = sigmoidf_(gx[0][r2][c2] + bc2 + zf*wl2);
      float ig = sigmoidf_(gx[1][r2][c2] + bc2 + zi*wl2);
      float gg = tanhf(    gx[2][r2][c2] + bc2 + zu*wl2);
      float og = sigmoidf_(gx[3][r2][c2] + bc2 + zo*wl2);
      float cn = fg*creg + ig*gg;
      creg = cn;
      float hn = og*tanhf(cn);
      size_t idx = (size_t)b2*H_SZ + h2;
      st_cc16(&hxb[idx], (__bf16)hn);
      __builtin_nontemporal_store(hn, &out[(size_t)s*B_SZ*H_SZ + idx]);
      if (s == S_LEN-1){
        __builtin_nontemporal_store(hn, &out[SBH + idx]);
        __builtin_nontemporal_store(cn, &out[SBH + (size_t)B_SZ*H_SZ + idx]);
      }
    }

    flag_bar(flags, (unsigned)(2*s+2));
  }
}

// ---------------- launch ----------------

extern "C" void kernel_launch(void* const* d_in, const int* in_sizes, int n_in,
                              void* d_out, int out_size, void* d_ws, size_t ws_size,
                              hipStream_t stream){
  const float* inputs = (const float*)d_in[0];
  const float* Wf  = (const float*)d_in[1];
  const float* bf_ = (const float*)d_in[2];
  const float* Wi  = (const float*)d_in[3];
  const float* bi_ = (const float*)d_in[4];
  const float* Wu  = (const float*)d_in[5];
  const float* bu_ = (const float*)d_in[6];
  const float* Wo  = (const float*)d_in[7];
  const float* bo_ = (const float*)d_in[8];
  const float* pf  = (const float*)d_in[9];
  const float* piq = (const float*)d_in[10];
  const float* pu  = (const float*)d_in[11];
  const float* po  = (const float*)d_in[12];
  const float* Wc  = (const float*)d_in[13];
  const float* bc  = (const float*)d_in[14];
  float* out = (float*)d_out;

  __bf16* W4p = (__bf16*)d_ws;                        // 6,291,456 bf16
  __bf16* Wcp = W4p + (size_t)256*48*64*8;            // 1,048,576 bf16
  __bf16* xb  = Wcp + (size_t)64*32*64*8;             // 8,388,608 bf16
  __bf16* act = xb  + (size_t)S_LEN*B_SZ*I_SZ;        // 262,144 bf16
  __bf16* hxb = act + (size_t)4*B_SZ*H_SZ;            // 65,536 bf16
  float*  zact = (float*)(hxb + (size_t)B_SZ*H_SZ);   // 256 f32
  unsigned* flags = (unsigned*)(zact + 256);          // 256 u32

  pack_w4_k<<<256*48, 64, 0, stream>>>(Wf, Wi, Wu, Wo, W4p);
  pack_wc_k<<<64*32, 64, 0, stream>>>(Wc, Wcp);
  cast_x_k<<<2048, 256, 0, stream>>>(inputs, xb, S_LEN*B_SZ*I_SZ);
  init_h_k<<<256, 256, 0, stream>>>(hxb);
  hipMemsetAsync(flags, 0, NBLK*sizeof(unsigned), stream);

  qlstm_persist_k<<<NBLK, 256, 0, stream>>>(
      xb, hxb, W4p, Wcp, bf_, bi_, bu_, bo_, pf, piq, pu, po,
      Wc + (size_t)H_SZ*H_SZ, bc, act, zact, out, flags);
}

// Round 7
// 4779.325 us; speedup vs baseline: 1.0480x; 1.0480x over previous
//
#include <hip/hip_runtime.h>

#define S_LEN 256
#define B_SZ 64
#define I_SZ 512
#define H_SZ 1024
#define NBLK 256

typedef __bf16 bf16x8 __attribute__((ext_vector_type(8)));
typedef float f32x4 __attribute__((ext_vector_type(4)));
typedef unsigned long long u64;

__device__ __forceinline__ float sigmoidf_(float x){ return 1.f/(1.f + expf(-x)); }

// ---- device-coherent (MALL) access helpers: bypass L1+L2, no fences ----
__device__ __forceinline__ u64 ld_cc64(const u64* p){
  return __hip_atomic_load(p, __ATOMIC_RELAXED, __HIP_MEMORY_SCOPE_AGENT);
}
__device__ __forceinline__ void st_cc16(__bf16* p, __bf16 v){
  unsigned short b = __builtin_bit_cast(unsigned short, v);
  __hip_atomic_store((unsigned short*)p, b, __ATOMIC_RELAXED, __HIP_MEMORY_SCOPE_AGENT);
}
__device__ __forceinline__ void st_cc32(float* p, float v){
  __hip_atomic_store(p, v, __ATOMIC_RELAXED, __HIP_MEMORY_SCOPE_AGENT);
}
__device__ __forceinline__ float ld_cc32f(const float* p){
  return __hip_atomic_load(p, __ATOMIC_RELAXED, __HIP_MEMORY_SCOPE_AGENT);
}

// ---------------- prep kernels ----------------

__global__ __launch_bounds__(64) void pack_w4_k(const float* __restrict__ Wf, const float* __restrict__ Wi,
                                                const float* __restrict__ Wu, const float* __restrict__ Wo,
                                                __bf16* __restrict__ W4p){
  int blk = blockIdx.x;           // nt16*48 + kb
  int nt = blk / 48, kb = blk % 48;
  int l = threadIdx.x;
  int n = nt*16 + (l & 15);
  int g = n >> 10, h = n & 1023;
  const float* W = (g==0)?Wf:((g==1)?Wi:((g==2)?Wu:Wo));
  int k0 = kb*32 + ((l>>4)<<3);
  __bf16 tmp[8];
#pragma unroll
  for (int j=0;j<8;j++) tmp[j] = (__bf16)W[(size_t)(k0+j)*H_SZ + h];
  *reinterpret_cast<bf16x8*>(W4p + ((size_t)blk*64 + l)*8) = *reinterpret_cast<bf16x8*>(tmp);
}

__global__ __launch_bounds__(64) void pack_wc_k(const float* __restrict__ Wc, __bf16* __restrict__ Wcp){
  int blk = blockIdx.x;           // nt16*32 + kb
  int nt = blk / 32, kb = blk % 32;
  int l = threadIdx.x;
  int n = nt*16 + (l & 15);
  int k0 = kb*32 + ((l>>4)<<3);
  __bf16 tmp[8];
#pragma unroll
  for (int j=0;j<8;j++) tmp[j] = (__bf16)Wc[(size_t)(k0+j)*H_SZ + n];
  *reinterpret_cast<bf16x8*>(Wcp + ((size_t)blk*64 + l)*8) = *reinterpret_cast<bf16x8*>(tmp);
}

// x packed into fragment order: xF[(s*4+mt)][kb 0..15][lane 0..63] 16B granules
__global__ __launch_bounds__(256) void pack_x_k(const float* __restrict__ x, __bf16* __restrict__ xF){
  int bid = blockIdx.x;           // s*4 + mt
  int s = bid >> 2, mt = bid & 3;
#pragma unroll
  for (int j=0;j<4;j++){
    int G = j*256 + threadIdx.x;  // granule 0..1023
    int kb = G >> 6, lane = G & 63;
    int b = mt*16 + (lane & 15);
    int k0 = kb*32 + ((lane>>4)<<3);
    const float* src = x + ((size_t)s*B_SZ + b)*I_SZ + k0;
    float4 v0 = *reinterpret_cast<const float4*>(src);
    float4 v1 = *reinterpret_cast<const float4*>(src+4);
    __bf16 t[8] = {(__bf16)v0.x,(__bf16)v0.y,(__bf16)v0.z,(__bf16)v0.w,
                   (__bf16)v1.x,(__bf16)v1.y,(__bf16)v1.z,(__bf16)v1.w};
    *reinterpret_cast<bf16x8*>(xF + ((size_t)bid*1024 + G)*8) = *reinterpret_cast<bf16x8*>(t);
  }
}

__global__ void init_h_k(__bf16* __restrict__ hxF){
  int i = blockIdx.x*blockDim.x + threadIdx.x;   // 65536 threads
  hxF[i] = (__bf16)0.f;
}

// ---------------- global flag-array grid barrier (round-4 verbatim) ----------------
__device__ __forceinline__ void flag_bar(unsigned* flags, unsigned target){
  asm volatile("" ::: "memory");
  __syncthreads();
  if (threadIdx.x == 0)
    __hip_atomic_store(&flags[blockIdx.x], target, __ATOMIC_RELAXED, __HIP_MEMORY_SCOPE_AGENT);
  if (threadIdx.x < 64){
    const u64* f = (const u64*)flags;
    int i0 = (int)threadIdx.x * 2;
    for(;;){
      u64 a = __hip_atomic_load(f+i0,   __ATOMIC_RELAXED, __HIP_MEMORY_SCOPE_AGENT);
      u64 b = __hip_atomic_load(f+i0+1, __ATOMIC_RELAXED, __HIP_MEMORY_SCOPE_AGENT);
      bool ok = ((unsigned)a >= target) && ((unsigned)(a>>32) >= target)
             && ((unsigned)b >= target) && ((unsigned)(b>>32) >= target);
      if (__all(ok)) break;
      __builtin_amdgcn_s_sleep(1);
    }
  }
  __syncthreads();
}

// ---------------- persistent kernel: all 256 steps ----------------
// Exchange buffers live in MFMA-fragment order in global memory:
//   hxF[grp 0..3][kb 0..31][lane 0..63]{8 bf16}: row grp*16+(lane&15),
//       h = kb*32 + (lane>>4)*8 .. +8
//   actF[g 0..3][oct 0..7][kb 0..31][slot 0..31]{8 bf16}: slot = kq8*8+r8,
//       row oct*8+r8, k = kb*32 + kq8*8 .. +8
// Consumer loads are coalesced (lane-contiguous granules) AND land directly
// in MFMA A-fragments -> no LDS staging at all.
// Phase 1: block (mt1, nt64): rows mt1*16..+16, cols nt64*64..+64; wave =
//          16-col tile; W4 frags in 192 VGPR; x from xF (L2), hx from hxF (MALL).
// Phase 2: block (mt2, ht): rows mt2*8..+8, h-cols ht*32..+32; wave = gate;
//          act frags direct from actF; Wc frags from LDS (persistent).

__global__ __launch_bounds__(256, 1) void qlstm_persist_k(
    const __bf16* __restrict__ xF,
    __bf16* hxF,
    const __bf16* __restrict__ W4p, const __bf16* __restrict__ Wcp,
    const float* __restrict__ bfv, const float* __restrict__ biv,
    const float* __restrict__ buv, const float* __restrict__ bov,
    const float* __restrict__ pf, const float* __restrict__ piq,
    const float* __restrict__ pu, const float* __restrict__ po,
    const float* __restrict__ WcLast, const float* __restrict__ bc,
    __bf16* actF, float* zact,
    float* __restrict__ out,
    unsigned* flags)
{
  __shared__ __align__(16) __bf16 ldsWc[2*32*64*8];   // 64 KiB, persistent
  __shared__ float gx[4][8][32];
  __shared__ float pre4[16][4];

  const int tid = threadIdx.x;
  const int bid = blockIdx.x;
  const int wave = tid >> 6;
  const int l = tid & 63;
  const int col = l & 15;
  const int kq = l >> 4;

  // ---- phase-1 ids ----
  const int mt1 = bid >> 6;
  const int nt64 = bid & 63;
  const int nt16 = nt64*4 + wave;
  const int g1 = nt16 >> 6;
  const int h1 = (nt16*16 + col) & 1023;

  // ---- phase-2 ids ----
  const int mt2 = bid >> 5;                // 0..7 -> 8-row batch tile
  const int ht  = bid & 31;                // 32 h-cols
  const int r2 = tid >> 5;
  const int c2 = tid & 31;
  const int b2 = mt2*8 + r2;
  const int h2 = ht*32 + c2;
  const int slot2 = kq*8 + (l & 7);        // A-frag slot (lanes l, l+8 share)

  // ---- W4 fragments -> registers (48 x bf16x8 = 192 VGPR) ----
  bf16x8 wfrag[48];
  {
    const bf16x8* src = (const bf16x8*)(W4p + ((size_t)nt16*48*64 + (size_t)l)*8);
#pragma unroll
    for (int kb=0;kb<48;kb++) wfrag[kb] = src[(size_t)kb*64];
  }
  // ---- Wc frags (nt16 = ht*2, ht*2+1) -> LDS, persistent ----
  {
    const u64* src = (const u64*)(Wcp + (size_t)(ht*2)*32*64*8);
    u64* dst = (u64*)ldsWc;
    for (int i = tid; i < 8192; i += 256) dst[i] = src[i];
  }

  const float* bptr = (g1==0)?bfv:((g1==1)?biv:((g1==2)?buv:bov));
  const float bias1 = bptr[h1];
  const bool isU1 = (g1==2);
  const bool isQb = ((nt64 & 15) == 0);
  const int gq = nt64 >> 4;
  float pq0=0.f,pq1=0.f,pq2=0.f,pq3=0.f;
  if (isQb && wave==0){
    const float* pq = (gq==0)?pf:((gq==1)?piq:((gq==2)?pu:po));
    pq0=pq[0]; pq1=pq[1]; pq2=pq[2]; pq3=pq[3];
  }

  const float wl2 = WcLast[h2];
  const float bc2 = bc[h2];
  float creg = 0.f;

  // precomputed store offsets
  // phase-2 hx store: hxF elem = ((grp*32 + kb)*64 + lane)*8 + e
  const int laneh = (b2 & 15) + (((c2 >> 3) & 3) << 4);
  const size_t hei = ((size_t)((b2>>4)*32 + ht)*64 + laneh)*8 + (c2 & 7);

  __syncthreads();   // Wc staged

  const size_t SBH = (size_t)S_LEN*B_SZ*H_SZ;

  for (int s = 0; s < S_LEN; ++s){
    // ================= phase 1: pre + activations + qgate =================
    {
      // hx fragment loads: coalesced (lane-contiguous), issue all 64 upfront
      const u64* hp = (const u64*)hxF + (size_t)mt1*4096 + (size_t)l*2;
      u64 hlo[32], hhi[32];
#pragma unroll
      for (int kb=0;kb<32;kb++){
        hlo[kb] = ld_cc64(hp + kb*128);
        hhi[kb] = ld_cc64(hp + kb*128 + 1);
      }
      // x fragment loads (L2/HBM, read-only)
      const bf16x8* xp = (const bf16x8*)xF + (size_t)(s*4 + mt1)*1024 + l;
      bf16x8 xf[16];
#pragma unroll
      for (int kb=0;kb<16;kb++) xf[kb] = xp[(size_t)kb*64];

      f32x4 acc[4] = {{0,0,0,0},{0,0,0,0},{0,0,0,0},{0,0,0,0}};
#pragma unroll
      for (int kb=0;kb<16;kb++)
        acc[kb&3] = __builtin_amdgcn_mfma_f32_16x16x32_bf16(xf[kb], wfrag[kb], acc[kb&3], 0,0,0);
#pragma unroll
      for (int kb=0;kb<32;kb++){
        union{u64 u[2]; bf16x8 v;} a; a.u[0]=hlo[kb]; a.u[1]=hhi[kb];
        acc[kb&3] = __builtin_amdgcn_mfma_f32_16x16x32_bf16(a.v, wfrag[16+kb], acc[kb&3], 0,0,0);
      }
      f32x4 r = (acc[0]+acc[1])+(acc[2]+acc[3]);
      float pr[4];
#pragma unroll
      for (int rr=0;rr<4;rr++){
        int brow = mt1*16 + (kq<<2) + rr;
        float p = r[rr] + bias1;
        pr[rr] = p;
        float a = isU1 ? tanhf(p) : sigmoidf_(p);
        // actF elem = (((g*8+oct)*32 + kb)*32 + slot)*8 + e
        size_t ei = (((size_t)(g1*8 + (brow>>3))*32 + (h1>>5))*32
                     + (size_t)((((h1>>3)&3)<<3) + (brow&7)))*8 + (h1&7);
        st_cc16(&actF[ei], (__bf16)a);
      }
      if (isQb && wave==0){
        if (col < 4){
#pragma unroll
          for (int rr=0;rr<4;rr++) pre4[(kq<<2)+rr][col] = pr[rr];
        }
        if (l < 16){
          float th = pre4[l][0]*pq0 + pre4[l][1]*pq1 + pre4[l][2]*pq2 + pre4[l][3]*pq3;
          float z = cosf(2.f*th);
          st_cc32(&zact[gq*B_SZ + mt1*16 + l], (gq==2) ? z : sigmoidf_(z));
        }
      }
    }

    flag_bar(flags, (unsigned)(2*s+1));

    // ================= phase 2: comb + cell update =================
    {
      // act fragment loads (own gate tile), coalesced, all 64 upfront
      const u64* ap = (const u64*)actF + (size_t)(wave*8 + mt2)*2048 + (size_t)slot2*2;
      u64 alo[32], ahi[32];
#pragma unroll
      for (int kb=0;kb<32;kb++){
        alo[kb] = ld_cc64(ap + kb*64);
        ahi[kb] = ld_cc64(ap + kb*64 + 1);
      }
      float zf = ld_cc32f(&zact[      b2]);
      float zi = ld_cc32f(&zact[ 64 + b2]);
      float zu = ld_cc32f(&zact[128 + b2]);
      float zo = ld_cc32f(&zact[192 + b2]);

      const bf16x8* bf0 = (const bf16x8*)ldsWc + l;
      const bf16x8* bf1 = bf0 + 2048;     // +32*64 frags
      f32x4 acc2[4] = {{0,0,0,0},{0,0,0,0},{0,0,0,0},{0,0,0,0}};
#pragma unroll
      for (int kb=0;kb<32;kb++){
        union{u64 u[2]; bf16x8 v;} a; a.u[0]=alo[kb]; a.u[1]=ahi[kb];
        acc2[kb&1]     = __builtin_amdgcn_mfma_f32_16x16x32_bf16(a.v, bf0[(size_t)kb*64], acc2[kb&1], 0,0,0);
        acc2[2+(kb&1)] = __builtin_amdgcn_mfma_f32_16x16x32_bf16(a.v, bf1[(size_t)kb*64], acc2[2+(kb&1)], 0,0,0);
      }
      f32x4 rA = acc2[0]+acc2[1];
      f32x4 rB = acc2[2]+acc2[3];
#pragma unroll
      for (int rr=0;rr<4;rr++){
        int row = (kq<<2) + rr;            // rows 8..15 are duplicates, discard
        if (row < 8){
          gx[wave][row][col]      = rA[rr];
          gx[wave][row][16 + col] = rB[rr];
        }
      }
      __syncthreads();

      float fg = sigmoidf_(gx[0][r2][c2] + bc2 + zf*wl2);
      float ig = sigmoidf_(gx[1][r2][c2] + bc2 + zi*wl2);
      float gg = tanhf(    gx[2][r2][c2] + bc2 + zu*wl2);
      float og = sigmoidf_(gx[3][r2][c2] + bc2 + zo*wl2);
      float cn = fg*creg + ig*gg;
      creg = cn;
      float hn = og*tanhf(cn);
      st_cc16(&hxF[hei], (__bf16)hn);
      size_t idx = (size_t)b2*H_SZ + h2;
      __builtin_nontemporal_store(hn, &out[(size_t)s*B_SZ*H_SZ + idx]);
      if (s == S_LEN-1){
        __builtin_nontemporal_store(hn, &out[SBH + idx]);
        __builtin_nontemporal_store(cn, &out[SBH + (size_t)B_SZ*H_SZ + idx]);
      }
    }

    flag_bar(flags, (unsigned)(2*s+2));
  }
}

// ---------------- launch ----------------

extern "C" void kernel_launch(void* const* d_in, const int* in_sizes, int n_in,
                              void* d_out, int out_size, void* d_ws, size_t ws_size,
                              hipStream_t stream){
  const float* inputs = (const float*)d_in[0];
  const float* Wf  = (const float*)d_in[1];
  const float* bf_ = (const float*)d_in[2];
  const float* Wi  = (const float*)d_in[3];
  const float* bi_ = (const float*)d_in[4];
  const float* Wu  = (const float*)d_in[5];
  const float* bu_ = (const float*)d_in[6];
  const float* Wo  = (const float*)d_in[7];
  const float* bo_ = (const float*)d_in[8];
  const float* pf  = (const float*)d_in[9];
  const float* piq = (const float*)d_in[10];
  const float* pu  = (const float*)d_in[11];
  const float* po  = (const float*)d_in[12];
  const float* Wc  = (const float*)d_in[13];
  const float* bc  = (const float*)d_in[14];
  float* out = (float*)d_out;

  __bf16* W4p = (__bf16*)d_ws;                        // 6,291,456 bf16
  __bf16* Wcp = W4p + (size_t)256*48*64*8;            // 1,048,576 bf16
  __bf16* xF  = Wcp + (size_t)64*32*64*8;             // 8,388,608 bf16
  __bf16* actF = xF + (size_t)S_LEN*B_SZ*I_SZ;        // 262,144 bf16
  __bf16* hxF = actF + (size_t)4*B_SZ*H_SZ;           // 65,536 bf16
  float*  zact = (float*)(hxF + (size_t)B_SZ*H_SZ);   // 256 f32
  unsigned* flags = (unsigned*)(zact + 256);          // 256 u32

  pack_w4_k<<<256*48, 64, 0, stream>>>(Wf, Wi, Wu, Wo, W4p);
  pack_wc_k<<<64*32, 64, 0, stream>>>(Wc, Wcp);
  pack_x_k<<<S_LEN*4, 256, 0, stream>>>(inputs, xF);
  init_h_k<<<256, 256, 0, stream>>>(hxF);
  hipMemsetAsync(flags, 0, NBLK*sizeof(unsigned), stream);

  qlstm_persist_k<<<NBLK, 256, 0, stream>>>(
      xF, hxF, W4p, Wcp, bf_, bi_, bu_, bo_, pf, piq, pu, po,
      Wc + (size_t)H_SZ*H_SZ, bc, actF, zact, out, flags);
}

// Round 8
// 3187.771 us; speedup vs baseline: 1.5713x; 1.4993x over previous
//
#include <hip/hip_runtime.h>

#define S_LEN 256
#define B_SZ 64
#define I_SZ 512
#define H_SZ 1024
#define NBLK 256

typedef __bf16 bf16x8 __attribute__((ext_vector_type(8)));
typedef float f32x4 __attribute__((ext_vector_type(4)));
typedef unsigned long long u64;

__device__ __forceinline__ float sigmoidf_(float x){ return 1.f/(1.f + expf(-x)); }

// ---- device-coherent (MALL) access helpers: bypass L1+L2, no fences ----
__device__ __forceinline__ u64 ld_cc64(const u64* p){
  return __hip_atomic_load(p, __ATOMIC_RELAXED, __HIP_MEMORY_SCOPE_AGENT);
}
__device__ __forceinline__ void st_cc16(__bf16* p, __bf16 v){
  unsigned short b = __builtin_bit_cast(unsigned short, v);
  __hip_atomic_store((unsigned short*)p, b, __ATOMIC_RELAXED, __HIP_MEMORY_SCOPE_AGENT);
}
__device__ __forceinline__ void st_cc32(float* p, float v){
  __hip_atomic_store(p, v, __ATOMIC_RELAXED, __HIP_MEMORY_SCOPE_AGENT);
}
__device__ __forceinline__ float ld_cc32f(const float* p){
  return __hip_atomic_load(p, __ATOMIC_RELAXED, __HIP_MEMORY_SCOPE_AGENT);
}

// ---------------- prep kernels ----------------

__global__ __launch_bounds__(64) void pack_w4_k(const float* __restrict__ Wf, const float* __restrict__ Wi,
                                                const float* __restrict__ Wu, const float* __restrict__ Wo,
                                                __bf16* __restrict__ W4p){
  int blk = blockIdx.x;           // nt16*48 + kb
  int nt = blk / 48, kb = blk % 48;
  int l = threadIdx.x;
  int n = nt*16 + (l & 15);
  int g = n >> 10, h = n & 1023;
  const float* W = (g==0)?Wf:((g==1)?Wi:((g==2)?Wu:Wo));
  int k0 = kb*32 + ((l>>4)<<3);
  __bf16 tmp[8];
#pragma unroll
  for (int j=0;j<8;j++) tmp[j] = (__bf16)W[(size_t)(k0+j)*H_SZ + h];
  *reinterpret_cast<bf16x8*>(W4p + ((size_t)blk*64 + l)*8) = *reinterpret_cast<bf16x8*>(tmp);
}

__global__ __launch_bounds__(64) void pack_wc_k(const float* __restrict__ Wc, __bf16* __restrict__ Wcp){
  int blk = blockIdx.x;           // nt16*32 + kb
  int nt = blk / 32, kb = blk % 32;
  int l = threadIdx.x;
  int n = nt*16 + (l & 15);
  int k0 = kb*32 + ((l>>4)<<3);
  __bf16 tmp[8];
#pragma unroll
  for (int j=0;j<8;j++) tmp[j] = (__bf16)Wc[(size_t)(k0+j)*H_SZ + n];
  *reinterpret_cast<bf16x8*>(Wcp + ((size_t)blk*64 + l)*8) = *reinterpret_cast<bf16x8*>(tmp);
}

// x packed into fragment order: xF[(s*4+mt)][kb 0..15][lane 0..63] 16B granules
__global__ __launch_bounds__(256) void pack_x_k(const float* __restrict__ x, __bf16* __restrict__ xF){
  int bid = blockIdx.x;           // s*4 + mt
  int s = bid >> 2, mt = bid & 3;
#pragma unroll
  for (int j=0;j<4;j++){
    int G = j*256 + threadIdx.x;  // granule 0..1023
    int kb = G >> 6, lane = G & 63;
    int b = mt*16 + (lane & 15);
    int k0 = kb*32 + ((lane>>4)<<3);
    const float* src = x + ((size_t)s*B_SZ + b)*I_SZ + k0;
    float4 v0 = *reinterpret_cast<const float4*>(src);
    float4 v1 = *reinterpret_cast<const float4*>(src+4);
    __bf16 t[8] = {(__bf16)v0.x,(__bf16)v0.y,(__bf16)v0.z,(__bf16)v0.w,
                   (__bf16)v1.x,(__bf16)v1.y,(__bf16)v1.z,(__bf16)v1.w};
    *reinterpret_cast<bf16x8*>(xF + ((size_t)bid*1024 + G)*8) = *reinterpret_cast<bf16x8*>(t);
  }
}

__global__ void init_h_k(__bf16* __restrict__ hxF){
  int i = blockIdx.x*blockDim.x + threadIdx.x;   // 65536 threads
  hxF[i] = (__bf16)0.f;
}

// ---------------- split arrive/wait flag barrier ----------------
// arrive: __syncthreads drains each wave's vmcnt(0) -> all coherent data
// stores are at the MALL before the flag store issues.
__device__ __forceinline__ void bar_arrive(unsigned* flags, unsigned target){
  asm volatile("" ::: "memory");
  __syncthreads();
  if (threadIdx.x == 0)
    __hip_atomic_store(&flags[blockIdx.x], target, __ATOMIC_RELAXED, __HIP_MEMORY_SCOPE_AGENT);
}
__device__ __forceinline__ void bar_wait(unsigned* flags, unsigned target){
  if (threadIdx.x < 64){
    const u64* f = (const u64*)flags;
    int i0 = (int)threadIdx.x * 2;
    for(;;){
      u64 a = __hip_atomic_load(f+i0,   __ATOMIC_RELAXED, __HIP_MEMORY_SCOPE_AGENT);
      u64 b = __hip_atomic_load(f+i0+1, __ATOMIC_RELAXED, __HIP_MEMORY_SCOPE_AGENT);
      bool ok = ((unsigned)a >= target) && ((unsigned)(a>>32) >= target)
             && ((unsigned)b >= target) && ((unsigned)(b>>32) >= target);
      if (__all(ok)) break;
      __builtin_amdgcn_s_sleep(1);
    }
  }
  __syncthreads();
}

// ---------------- persistent kernel: all 256 steps ----------------
// Exchange buffers in MFMA-fragment order in global memory (r7 layout):
//   hxF[mt 0..3][kb 0..31][lane 0..63]{8 bf16}
//   actF[g 0..3][oct 0..7][kb 0..31][slot 0..31]{8 bf16}, slot = kq*8+r8
// This round: stage them into LDS ONCE per block (flat identity memcpy:
// coalesced 16B global loads -> lane-contiguous ds_write_b128; consumers
// ds_read_b128 lane-contiguous) -> conflict-free AND coalesced AND 1x volume.
// Phase 1: block (mt1, nt64); wave = 16-col tile; W4 frags in 192 VGPR;
//          x-part loads+MFMAs issued BEFORE the barrier wait (read-only).
// Phase 2: block (mt2, ht); wave = gate; Wc frags in LDS (persistent).

__global__ __launch_bounds__(256, 1) void qlstm_persist_k(
    const __bf16* __restrict__ xF,
    __bf16* hxF,
    const __bf16* __restrict__ W4p, const __bf16* __restrict__ Wcp,
    const float* __restrict__ bfv, const float* __restrict__ biv,
    const float* __restrict__ buv, const float* __restrict__ bov,
    const float* __restrict__ pf, const float* __restrict__ piq,
    const float* __restrict__ pu, const float* __restrict__ po,
    const float* __restrict__ WcLast, const float* __restrict__ bc,
    __bf16* actF, float* zact,
    float* __restrict__ out,
    unsigned* flags)
{
  __shared__ __align__(16) __bf16 ldsWc[2*32*64*8];   // 64 KiB, persistent
  __shared__ __align__(16) char ldsA[65536];          // stage: p1 32K (hx), p2 64K (act)
  __shared__ float gx[4][8][32];
  __shared__ float pre4[16][4];

  const int tid = threadIdx.x;
  const int bid = blockIdx.x;
  const int wave = tid >> 6;
  const int l = tid & 63;
  const int col = l & 15;
  const int kq = l >> 4;

  // ---- phase-1 ids ----
  const int mt1 = bid >> 6;
  const int nt64 = bid & 63;
  const int nt16 = nt64*4 + wave;
  const int g1 = nt16 >> 6;
  const int h1 = (nt16*16 + col) & 1023;

  // ---- phase-2 ids ----
  const int mt2 = bid >> 5;                // 0..7 -> 8-row batch tile
  const int ht  = bid & 31;                // 32 h-cols
  const int r2 = tid >> 5;
  const int c2 = tid & 31;
  const int b2 = mt2*8 + r2;
  const int h2 = ht*32 + c2;
  const int slot2 = kq*8 + (l & 7);        // A-frag slot (lanes l, l+8 share)

  // ---- W4 fragments -> registers (48 x bf16x8 = 192 VGPR) ----
  bf16x8 wfrag[48];
  {
    const bf16x8* src = (const bf16x8*)(W4p + ((size_t)nt16*48*64 + (size_t)l)*8);
#pragma unroll
    for (int kb=0;kb<48;kb++) wfrag[kb] = src[(size_t)kb*64];
  }
  // ---- Wc frags (nt16 = ht*2, ht*2+1) -> LDS, persistent ----
  {
    const u64* src = (const u64*)(Wcp + (size_t)(ht*2)*32*64*8);
    u64* dst = (u64*)ldsWc;
    for (int i = tid; i < 8192; i += 256) dst[i] = src[i];
  }

  const float* bptr = (g1==0)?bfv:((g1==1)?biv:((g1==2)?buv:bov));
  const float bias1 = bptr[h1];
  const bool isU1 = (g1==2);
  const bool isQb = ((nt64 & 15) == 0);
  const int gq = nt64 >> 4;
  float pq0=0.f,pq1=0.f,pq2=0.f,pq3=0.f;
  if (isQb && wave==0){
    const float* pq = (gq==0)?pf:((gq==1)?piq:((gq==2)?pu:po));
    pq0=pq[0]; pq1=pq[1]; pq2=pq[2]; pq3=pq[3];
  }

  const float wl2 = WcLast[h2];
  const float bc2 = bc[h2];
  float creg = 0.f;

  // phase-2 hx store: hxF elem = ((grp*32 + kb)*64 + lane)*8 + e
  const int laneh = (b2 & 15) + (((c2 >> 3) & 3) << 4);
  const size_t hei = ((size_t)((b2>>4)*32 + ht)*64 + laneh)*8 + (c2 & 7);

  __syncthreads();   // Wc staged

  const size_t SBH = (size_t)S_LEN*B_SZ*H_SZ;

  for (int s = 0; s < S_LEN; ++s){
    // ================= phase 1: pre + activations + qgate =================
    {
      f32x4 acc[4] = {{0,0,0,0},{0,0,0,0},{0,0,0,0},{0,0,0,0}};
      // x-part (read-only, L2): loads + MFMAs BEFORE barrier wait
      const bf16x8* xp = (const bf16x8*)xF + (size_t)(s*4 + mt1)*1024 + l;
      {
        bf16x8 xf[8];
#pragma unroll
        for (int j=0;j<8;j++) xf[j] = xp[(size_t)j*64];
#pragma unroll
        for (int j=0;j<8;j++)
          acc[j&3] = __builtin_amdgcn_mfma_f32_16x16x32_bf16(xf[j], wfrag[j], acc[j&3], 0,0,0);
#pragma unroll
        for (int j=0;j<8;j++) xf[j] = xp[(size_t)(8+j)*64];
#pragma unroll
        for (int j=0;j<8;j++)
          acc[j&3] = __builtin_amdgcn_mfma_f32_16x16x32_bf16(xf[j], wfrag[8+j], acc[j&3], 0,0,0);
      }

      bar_wait(flags, (unsigned)(2*s));    // p2(s-1) done (no-op at s=0: target 0)

      // stage hx (identity memcpy: coalesced loads -> contiguous ds_write)
      {
        const u64* hp = (const u64*)hxF + (size_t)mt1*4096;
        u64 slo[8], shi[8];
#pragma unroll
        for (int i=0;i<8;i++){
          int G = tid + 256*i;
          slo[i] = ld_cc64(hp + (size_t)G*2);
          shi[i] = ld_cc64(hp + (size_t)G*2 + 1);
        }
#pragma unroll
        for (int i=0;i<8;i++){
          int G = tid + 256*i;
          ulonglong2 v; v.x = slo[i]; v.y = shi[i];
          *reinterpret_cast<ulonglong2*>(ldsA + (size_t)G*16) = v;
        }
      }
      __syncthreads();

#pragma unroll
      for (int kb=0;kb<32;kb++){
        bf16x8 a = *reinterpret_cast<const bf16x8*>(ldsA + ((size_t)kb*64 + l)*16);
        acc[kb&3] = __builtin_amdgcn_mfma_f32_16x16x32_bf16(a, wfrag[16+kb], acc[kb&3], 0,0,0);
      }
      f32x4 r = (acc[0]+acc[1])+(acc[2]+acc[3]);
      float pr[4];
#pragma unroll
      for (int rr=0;rr<4;rr++){
        int brow = mt1*16 + (kq<<2) + rr;
        float p = r[rr] + bias1;
        pr[rr] = p;
        float a = isU1 ? tanhf(p) : sigmoidf_(p);
        // actF elem = (((g*8+oct)*32 + kb)*32 + slot)*8 + e
        size_t ei = (((size_t)(g1*8 + (brow>>3))*32 + (h1>>5))*32
                     + (size_t)((((h1>>3)&3)<<3) + (brow&7)))*8 + (h1&7);
        st_cc16(&actF[ei], (__bf16)a);
      }
      if (isQb && wave==0){
        if (col < 4){
#pragma unroll
          for (int rr=0;rr<4;rr++) pre4[(kq<<2)+rr][col] = pr[rr];
        }
        if (l < 16){
          float th = pre4[l][0]*pq0 + pre4[l][1]*pq1 + pre4[l][2]*pq2 + pre4[l][3]*pq3;
          float z = cosf(2.f*th);
          st_cc32(&zact[gq*B_SZ + mt1*16 + l], (gq==2) ? z : sigmoidf_(z));
        }
      }
    }

    bar_arrive(flags, (unsigned)(2*s+1));
    bar_wait(flags, (unsigned)(2*s+1));

    // ================= phase 2: comb + cell update =================
    {
      // stage act (identity memcpy), 64 KB: granule gi = (g*32+kb)*32+slot
      {
        u64 alo[16], ahi[16];
#pragma unroll
        for (int i=0;i<16;i++){
          int gi = tid + 256*i;
          int slot = gi & 31;
          int kbg = gi >> 5;               // 0..127: g*32+kb
          int gg = kbg >> 5, kb = kbg & 31;
          size_t Gg = (size_t)gg*8192 + (size_t)mt2*1024 + (size_t)kb*32 + slot;
          alo[i] = ld_cc64((const u64*)actF + Gg*2);
          ahi[i] = ld_cc64((const u64*)actF + Gg*2 + 1);
        }
#pragma unroll
        for (int i=0;i<16;i++){
          int gi = tid + 256*i;
          ulonglong2 v; v.x = alo[i]; v.y = ahi[i];
          *reinterpret_cast<ulonglong2*>(ldsA + (size_t)gi*16) = v;
        }
      }
      float zf = ld_cc32f(&zact[      b2]);
      float zi = ld_cc32f(&zact[ 64 + b2]);
      float zu = ld_cc32f(&zact[128 + b2]);
      float zo = ld_cc32f(&zact[192 + b2]);
      __syncthreads();

      // wave = gate: A-frags from LDS, B-frags (Wc) from LDS
      const char* Ab = ldsA + (size_t)wave*16384;
      const bf16x8* bf0 = (const bf16x8*)ldsWc + l;
      const bf16x8* bf1 = bf0 + 2048;
      f32x4 acc2[4] = {{0,0,0,0},{0,0,0,0},{0,0,0,0},{0,0,0,0}};
#pragma unroll
      for (int kb=0;kb<32;kb++){
        bf16x8 a = *reinterpret_cast<const bf16x8*>(Ab + (size_t)kb*512 + (size_t)slot2*16);
        acc2[kb&1]     = __builtin_amdgcn_mfma_f32_16x16x32_bf16(a, bf0[(size_t)kb*64], acc2[kb&1], 0,0,0);
        acc2[2+(kb&1)] = __builtin_amdgcn_mfma_f32_16x16x32_bf16(a, bf1[(size_t)kb*64], acc2[2+(kb&1)], 0,0,0);
      }
      f32x4 rA = acc2[0]+acc2[1];
      f32x4 rB = acc2[2]+acc2[3];
#pragma unroll
      for (int rr=0;rr<4;rr++){
        int row = (kq<<2) + rr;            // rows 8..15 duplicates, discard
        if (row < 8){
          gx[wave][row][col]      = rA[rr];
          gx[wave][row][16 + col] = rB[rr];
        }
      }
      __syncthreads();

      float fg = sigmoidf_(gx[0][r2][c2] + bc2 + zf*wl2);
      float ig = sigmoidf_(gx[1][r2][c2] + bc2 + zi*wl2);
      float gg = tanhf(    gx[2][r2][c2] + bc2 + zu*wl2);
      float og = sigmoidf_(gx[3][r2][c2] + bc2 + zo*wl2);
      float cn = fg*creg + ig*gg;
      creg = cn;
      float hn = og*tanhf(cn);
      st_cc16(&hxF[hei], (__bf16)hn);
      size_t idx = (size_t)b2*H_SZ + h2;
      __builtin_nontemporal_store(hn, &out[(size_t)s*B_SZ*H_SZ + idx]);
      if (s == S_LEN-1){
        __builtin_nontemporal_store(hn, &out[SBH + idx]);
        __builtin_nontemporal_store(cn, &out[SBH + (size_t)B_SZ*H_SZ + idx]);
      }
    }

    bar_arrive(flags, (unsigned)(2*s+2));
  }
}

// ---------------- launch ----------------

extern "C" void kernel_launch(void* const* d_in, const int* in_sizes, int n_in,
                              void* d_out, int out_size, void* d_ws, size_t ws_size,
                              hipStream_t stream){
  const float* inputs = (const float*)d_in[0];
  const float* Wf  = (const float*)d_in[1];
  const float* bf_ = (const float*)d_in[2];
  const float* Wi  = (const float*)d_in[3];
  const float* bi_ = (const float*)d_in[4];
  const float* Wu  = (const float*)d_in[5];
  const float* bu_ = (const float*)d_in[6];
  const float* Wo  = (const float*)d_in[7];
  const float* bo_ = (const float*)d_in[8];
  const float* pf  = (const float*)d_in[9];
  const float* piq = (const float*)d_in[10];
  const float* pu  = (const float*)d_in[11];
  const float* po  = (const float*)d_in[12];
  const float* Wc  = (const float*)d_in[13];
  const float* bc  = (const float*)d_in[14];
  float* out = (float*)d_out;

  __bf16* W4p = (__bf16*)d_ws;                        // 6,291,456 bf16
  __bf16* Wcp = W4p + (size_t)256*48*64*8;            // 1,048,576 bf16
  __bf16* xF  = Wcp + (size_t)64*32*64*8;             // 8,388,608 bf16
  __bf16* actF = xF + (size_t)S_LEN*B_SZ*I_SZ;        // 262,144 bf16
  __bf16* hxF = actF + (size_t)4*B_SZ*H_SZ;           // 65,536 bf16
  float*  zact = (float*)(hxF + (size_t)B_SZ*H_SZ);   // 256 f32
  unsigned* flags = (unsigned*)(zact + 256);          // 256 u32

  pack_w4_k<<<256*48, 64, 0, stream>>>(Wf, Wi, Wu, Wo, W4p);
  pack_wc_k<<<64*32, 64, 0, stream>>>(Wc, Wcp);
  pack_x_k<<<S_LEN*4, 256, 0, stream>>>(inputs, xF);
  init_h_k<<<256, 256, 0, stream>>>(hxF);
  hipMemsetAsync(flags, 0, NBLK*sizeof(unsigned), stream);

  qlstm_persist_k<<<NBLK, 256, 0, stream>>>(
      xF, hxF, W4p, Wcp, bf_, bi_, bu_, bo_, pf, piq, pu, po,
      Wc + (size_t)H_SZ*H_SZ, bc, actF, zact, out, flags);
}

// Round 11
// 2932.378 us; speedup vs baseline: 1.7081x; 1.0871x over previous
//
#include <hip/hip_runtime.h>

#define S_LEN 256
#define B_SZ 64
#define I_SZ 512
#define H_SZ 1024
#define NBLK 256

typedef __bf16 bf16x8 __attribute__((ext_vector_type(8)));
typedef float f32x4 __attribute__((ext_vector_type(4)));
typedef unsigned long long u64;

__device__ __forceinline__ float sigmoidf_(float x){ return 1.f/(1.f + expf(-x)); }

// ---- device-coherent (MALL) access helpers: bypass L1+L2, no fences ----
__device__ __forceinline__ u64 ld_cc64(const u64* p){
  return __hip_atomic_load(p, __ATOMIC_RELAXED, __HIP_MEMORY_SCOPE_AGENT);
}
__device__ __forceinline__ void st_cc16(__bf16* p, __bf16 v){
  unsigned short b = __builtin_bit_cast(unsigned short, v);
  __hip_atomic_store((unsigned short*)p, b, __ATOMIC_RELAXED, __HIP_MEMORY_SCOPE_AGENT);
}
__device__ __forceinline__ void st_cc32(float* p, float v){
  __hip_atomic_store(p, v, __ATOMIC_RELAXED, __HIP_MEMORY_SCOPE_AGENT);
}
__device__ __forceinline__ float ld_cc32f(const float* p){
  return __hip_atomic_load(p, __ATOMIC_RELAXED, __HIP_MEMORY_SCOPE_AGENT);
}

// ---------------- prep kernels ----------------

__global__ __launch_bounds__(64) void pack_w4_k(const float* __restrict__ Wf, const float* __restrict__ Wi,
                                                const float* __restrict__ Wu, const float* __restrict__ Wo,
                                                __bf16* __restrict__ W4p){
  int blk = blockIdx.x;           // nt16*48 + kb
  int nt = blk / 48, kb = blk % 48;
  int l = threadIdx.x;
  int n = nt*16 + (l & 15);
  int g = n >> 10, h = n & 1023;
  const float* W = (g==0)?Wf:((g==1)?Wi:((g==2)?Wu:Wo));
  int k0 = kb*32 + ((l>>4)<<3);
  __bf16 tmp[8];
#pragma unroll
  for (int j=0;j<8;j++) tmp[j] = (__bf16)W[(size_t)(k0+j)*H_SZ + h];
  *reinterpret_cast<bf16x8*>(W4p + ((size_t)blk*64 + l)*8) = *reinterpret_cast<bf16x8*>(tmp);
}

__global__ __launch_bounds__(64) void pack_wc_k(const float* __restrict__ Wc, __bf16* __restrict__ Wcp){
  int blk = blockIdx.x;           // nt16*32 + kb
  int nt = blk / 32, kb = blk % 32;
  int l = threadIdx.x;
  int n = nt*16 + (l & 15);
  int k0 = kb*32 + ((l>>4)<<3);
  __bf16 tmp[8];
#pragma unroll
  for (int j=0;j<8;j++) tmp[j] = (__bf16)Wc[(size_t)(k0+j)*H_SZ + n];
  *reinterpret_cast<bf16x8*>(Wcp + ((size_t)blk*64 + l)*8) = *reinterpret_cast<bf16x8*>(tmp);
}

// x packed into fragment order: xF[(s*4+mt)][kb 0..15][lane 0..63] 16B granules
__global__ __launch_bounds__(256) void pack_x_k(const float* __restrict__ x, __bf16* __restrict__ xF){
  int bid = blockIdx.x;           // s*4 + mt
  int s = bid >> 2, mt = bid & 3;
#pragma unroll
  for (int j=0;j<4;j++){
    int G = j*256 + threadIdx.x;  // granule 0..1023
    int kb = G >> 6, lane = G & 63;
    int b = mt*16 + (lane & 15);
    int k0 = kb*32 + ((lane>>4)<<3);
    const float* src = x + ((size_t)s*B_SZ + b)*I_SZ + k0;
    float4 v0 = *reinterpret_cast<const float4*>(src);
    float4 v1 = *reinterpret_cast<const float4*>(src+4);
    __bf16 t[8] = {(__bf16)v0.x,(__bf16)v0.y,(__bf16)v0.z,(__bf16)v0.w,
                   (__bf16)v1.x,(__bf16)v1.y,(__bf16)v1.z,(__bf16)v1.w};
    *reinterpret_cast<bf16x8*>(xF + ((size_t)bid*1024 + G)*8) = *reinterpret_cast<bf16x8*>(t);
  }
}

__global__ void init_h_k(__bf16* __restrict__ hxF){
  int i = blockIdx.x*blockDim.x + threadIdx.x;   // 65536 threads
  hxF[i] = (__bf16)0.f;
}

// ------------- group-local split arrive/wait flag barrier (64 blocks) -------------
// Dataflow is fully group-local (group = 16 batch rows = blocks [64g,64g+64)),
// so each group syncs only its own 64 flags: one 256B line, 4 independent domains.
// arrive: __syncthreads drains each wave's vmcnt(0) -> all coherent data stores
// are at the MALL before the flag store issues.
__device__ __forceinline__ void bar_arrive(unsigned* flags, int gbase, int sub, unsigned target){
  asm volatile("" ::: "memory");
  __syncthreads();
  if (threadIdx.x == 0)
    __hip_atomic_store(&flags[gbase + sub], target, __ATOMIC_RELAXED, __HIP_MEMORY_SCOPE_AGENT);
}
__device__ __forceinline__ void bar_wait(const unsigned* flags, int gbase, unsigned target){
  if (threadIdx.x < 64){
    const unsigned* f = flags + gbase + threadIdx.x;
    for(;;){
      unsigned v = __hip_atomic_load(f, __ATOMIC_RELAXED, __HIP_MEMORY_SCOPE_AGENT);
      if (__all(v >= target)) break;
      __builtin_amdgcn_s_sleep(1);
    }
  }
  __syncthreads();
}

// ---------------- persistent kernel: all 256 steps ----------------
// Identical to round 8 except the barrier is group-local.
// Exchange buffers in MFMA-fragment order in global memory:
//   hxF[mt 0..3][kb 0..31][lane 0..63]{8 bf16}
//   actF[g 0..3][oct 0..7][kb 0..31][slot 0..31]{8 bf16}, slot = kq*8+r8
// Staged into LDS once per block (flat identity memcpy: coalesced 16B global
// loads -> lane-contiguous ds_write_b128 -> conflict-free ds_read_b128).
// Phase 1: block (mt1=g, nt64); wave = 16-col tile; W4 frags in 192 VGPR;
//          x-part loads+MFMAs issued BEFORE the barrier wait (read-only).
// Phase 2: block (mt2 in {2g,2g+1}, ht); wave = gate; Wc frags in LDS.

__global__ __launch_bounds__(256, 1) void qlstm_persist_k(
    const __bf16* __restrict__ xF,
    __bf16* hxF,
    const __bf16* __restrict__ W4p, const __bf16* __restrict__ Wcp,
    const float* __restrict__ bfv, const float* __restrict__ biv,
    const float* __restrict__ buv, const float* __restrict__ bov,
    const float* __restrict__ pf, const float* __restrict__ piq,
    const float* __restrict__ pu, const float* __restrict__ po,
    const float* __restrict__ WcLast, const float* __restrict__ bc,
    __bf16* actF, float* zact,
    float* __restrict__ out,
    unsigned* flags)
{
  __shared__ __align__(16) __bf16 ldsWc[2*32*64*8];   // 64 KiB, persistent
  __shared__ __align__(16) char ldsA[65536];          // stage: p1 32K (hx), p2 64K (act)
  __shared__ float gx[4][8][32];
  __shared__ float pre4[16][4];

  const int tid = threadIdx.x;
  const int bid = blockIdx.x;
  const int wave = tid >> 6;
  const int l = tid & 63;
  const int col = l & 15;
  const int kq = l >> 4;

  // ---- group ids ----
  const int grp = bid >> 6;                // 0..3: owns batch rows 16*grp..+16
  const int sub = bid & 63;
  const int gbase = grp * 64;

  // ---- phase-1 ids ----
  const int mt1 = grp;
  const int nt64 = sub;
  const int nt16 = nt64*4 + wave;
  const int g1 = nt16 >> 6;
  const int h1 = (nt16*16 + col) & 1023;

  // ---- phase-2 ids ----
  const int mt2 = bid >> 5;                // in {2g, 2g+1} -> 8-row batch tile
  const int ht  = bid & 31;                // 32 h-cols
  const int r2 = tid >> 5;
  const int c2 = tid & 31;
  const int b2 = mt2*8 + r2;
  const int h2 = ht*32 + c2;
  const int slot2 = kq*8 + (l & 7);        // A-frag slot (lanes l, l+8 share)

  // ---- W4 fragments -> registers (48 x bf16x8 = 192 VGPR) ----
  bf16x8 wfrag[48];
  {
    const bf16x8* src = (const bf16x8*)(W4p + ((size_t)nt16*48*64 + (size_t)l)*8);
#pragma unroll
    for (int kb=0;kb<48;kb++) wfrag[kb] = src[(size_t)kb*64];
  }
  // ---- Wc frags (nt16 = ht*2, ht*2+1) -> LDS, persistent ----
  {
    const u64* src = (const u64*)(Wcp + (size_t)(ht*2)*32*64*8);
    u64* dst = (u64*)ldsWc;
    for (int i = tid; i < 8192; i += 256) dst[i] = src[i];
  }

  const float* bptr = (g1==0)?bfv:((g1==1)?biv:((g1==2)?buv:bov));
  const float bias1 = bptr[h1];
  const bool isU1 = (g1==2);
  const bool isQb = ((nt64 & 15) == 0);
  const int gq = nt64 >> 4;
  float pq0=0.f,pq1=0.f,pq2=0.f,pq3=0.f;
  if (isQb && wave==0){
    const float* pq = (gq==0)?pf:((gq==1)?piq:((gq==2)?pu:po));
    pq0=pq[0]; pq1=pq[1]; pq2=pq[2]; pq3=pq[3];
  }

  const float wl2 = WcLast[h2];
  const float bc2 = bc[h2];
  float creg = 0.f;

  // phase-2 hx store: hxF elem = ((grp*32 + kb)*64 + lane)*8 + e
  const int laneh = (b2 & 15) + (((c2 >> 3) & 3) << 4);
  const size_t hei = ((size_t)((b2>>4)*32 + ht)*64 + laneh)*8 + (c2 & 7);

  __syncthreads();   // Wc staged

  const size_t SBH = (size_t)S_LEN*B_SZ*H_SZ;

  for (int s = 0; s < S_LEN; ++s){
    // ================= phase 1: pre + activations + qgate =================
    {
      f32x4 acc[4] = {{0,0,0,0},{0,0,0,0},{0,0,0,0},{0,0,0,0}};
      // x-part (read-only, L2): loads + MFMAs BEFORE barrier wait
      const bf16x8* xp = (const bf16x8*)xF + (size_t)(s*4 + mt1)*1024 + l;
      {
        bf16x8 xf[8];
#pragma unroll
        for (int j=0;j<8;j++) xf[j] = xp[(size_t)j*64];
#pragma unroll
        for (int j=0;j<8;j++)
          acc[j&3] = __builtin_amdgcn_mfma_f32_16x16x32_bf16(xf[j], wfrag[j], acc[j&3], 0,0,0);
#pragma unroll
        for (int j=0;j<8;j++) xf[j] = xp[(size_t)(8+j)*64];
#pragma unroll
        for (int j=0;j<8;j++)
          acc[j&3] = __builtin_amdgcn_mfma_f32_16x16x32_bf16(xf[j], wfrag[8+j], acc[j&3], 0,0,0);
      }

      bar_wait(flags, gbase, (unsigned)(2*s));   // own group's p2(s-1) done

      // stage hx (identity memcpy: coalesced loads -> contiguous ds_write)
      {
        const u64* hp = (const u64*)hxF + (size_t)mt1*4096;
        u64 slo[8], shi[8];
#pragma unroll
        for (int i=0;i<8;i++){
          int G = tid + 256*i;
          slo[i] = ld_cc64(hp + (size_t)G*2);
          shi[i] = ld_cc64(hp + (size_t)G*2 + 1);
        }
#pragma unroll
        for (int i=0;i<8;i++){
          int G = tid + 256*i;
          ulonglong2 v; v.x = slo[i]; v.y = shi[i];
          *reinterpret_cast<ulonglong2*>(ldsA + (size_t)G*16) = v;
        }
      }
      __syncthreads();

#pragma unroll
      for (int kb=0;kb<32;kb++){
        bf16x8 a = *reinterpret_cast<const bf16x8*>(ldsA + ((size_t)kb*64 + l)*16);
        acc[kb&3] = __builtin_amdgcn_mfma_f32_16x16x32_bf16(a, wfrag[16+kb], acc[kb&3], 0,0,0);
      }
      f32x4 r = (acc[0]+acc[1])+(acc[2]+acc[3]);
      float pr[4];
#pragma unroll
      for (int rr=0;rr<4;rr++){
        int brow = mt1*16 + (kq<<2) + rr;
        float p = r[rr] + bias1;
        pr[rr] = p;
        float a = isU1 ? tanhf(p) : sigmoidf_(p);
        // actF elem = (((g*8+oct)*32 + kb)*32 + slot)*8 + e
        size_t ei = (((size_t)(g1*8 + (brow>>3))*32 + (h1>>5))*32
                     + (size_t)((((h1>>3)&3)<<3) + (brow&7)))*8 + (h1&7);
        st_cc16(&actF[ei], (__bf16)a);
      }
      if (isQb && wave==0){
        if (col < 4){
#pragma unroll
          for (int rr=0;rr<4;rr++) pre4[(kq<<2)+rr][col] = pr[rr];
        }
        if (l < 16){
          float th = pre4[l][0]*pq0 + pre4[l][1]*pq1 + pre4[l][2]*pq2 + pre4[l][3]*pq3;
          float z = cosf(2.f*th);
          st_cc32(&zact[gq*B_SZ + mt1*16 + l], (gq==2) ? z : sigmoidf_(z));
        }
      }
    }

    bar_arrive(flags, gbase, sub, (unsigned)(2*s+1));
    bar_wait(flags, gbase, (unsigned)(2*s+1));

    // ================= phase 2: comb + cell update =================
    {
      // stage act (identity memcpy), 64 KB: granule gi = (g*32+kb)*32+slot
      {
        u64 alo[16], ahi[16];
#pragma unroll
        for (int i=0;i<16;i++){
          int gi = tid + 256*i;
          int slot = gi & 31;
          int kbg = gi >> 5;               // 0..127: g*32+kb
          int gg = kbg >> 5, kb = kbg & 31;
          size_t Gg = (size_t)gg*8192 + (size_t)mt2*1024 + (size_t)kb*32 + slot;
          alo[i] = ld_cc64((const u64*)actF + Gg*2);
          ahi[i] = ld_cc64((const u64*)actF + Gg*2 + 1);
        }
#pragma unroll
        for (int i=0;i<16;i++){
          int gi = tid + 256*i;
          ulonglong2 v; v.x = alo[i]; v.y = ahi[i];
          *reinterpret_cast<ulonglong2*>(ldsA + (size_t)gi*16) = v;
        }
      }
      float zf = ld_cc32f(&zact[      b2]);
      float zi = ld_cc32f(&zact[ 64 + b2]);
      float zu = ld_cc32f(&zact[128 + b2]);
      float zo = ld_cc32f(&zact[192 + b2]);
      __syncthreads();

      // wave = gate: A-frags from LDS, B-frags (Wc) from LDS
      const char* Ab = ldsA + (size_t)wave*16384;
      const bf16x8* bf0 = (const bf16x8*)ldsWc + l;
      const bf16x8* bf1 = bf0 + 2048;
      f32x4 acc2[4] = {{0,0,0,0},{0,0,0,0},{0,0,0,0},{0,0,0,0}};
#pragma unroll
      for (int kb=0;kb<32;kb++){
        bf16x8 a = *reinterpret_cast<const bf16x8*>(Ab + (size_t)kb*512 + (size_t)slot2*16);
        acc2[kb&1]     = __builtin_amdgcn_mfma_f32_16x16x32_bf16(a, bf0[(size_t)kb*64], acc2[kb&1], 0,0,0);
        acc2[2+(kb&1)] = __builtin_amdgcn_mfma_f32_16x16x32_bf16(a, bf1[(size_t)kb*64], acc2[2+(kb&1)], 0,0,0);
      }
      f32x4 rA = acc2[0]+acc2[1];
      f32x4 rB = acc2[2]+acc2[3];
#pragma unroll
      for (int rr=0;rr<4;rr++){
        int row = (kq<<2) + rr;            // rows 8..15 duplicates, discard
        if (row < 8){
          gx[wave][row][col]      = rA[rr];
          gx[wave][row][16 + col] = rB[rr];
        }
      }
      __syncthreads();

      float fg = sigmoidf_(gx[0][r2][c2] + bc2 + zf*wl2);
      float ig = sigmoidf_(gx[1][r2][c2] + bc2 + zi*wl2);
      float gg = tanhf(    gx[2][r2][c2] + bc2 + zu*wl2);
      float og = sigmoidf_(gx[3][r2][c2] + bc2 + zo*wl2);
      float cn = fg*creg + ig*gg;
      creg = cn;
      float hn = og*tanhf(cn);
      st_cc16(&hxF[hei], (__bf16)hn);
      size_t idx = (size_t)b2*H_SZ + h2;
      __builtin_nontemporal_store(hn, &out[(size_t)s*B_SZ*H_SZ + idx]);
      if (s == S_LEN-1){
        __builtin_nontemporal_store(hn, &out[SBH + idx]);
        __builtin_nontemporal_store(cn, &out[SBH + (size_t)B_SZ*H_SZ + idx]);
      }
    }

    bar_arrive(flags, gbase, sub, (unsigned)(2*s+2));
  }
}

// ---------------- launch ----------------

extern "C" void kernel_launch(void* const* d_in, const int* in_sizes, int n_in,
                              void* d_out, int out_size, void* d_ws, size_t ws_size,
                              hipStream_t stream){
  const float* inputs = (const float*)d_in[0];
  const float* Wf  = (const float*)d_in[1];
  const float* bf_ = (const float*)d_in[2];
  const float* Wi  = (const float*)d_in[3];
  const float* bi_ = (const float*)d_in[4];
  const float* Wu  = (const float*)d_in[5];
  const float* bu_ = (const float*)d_in[6];
  const float* Wo  = (const float*)d_in[7];
  const float* bo_ = (const float*)d_in[8];
  const float* pf  = (const float*)d_in[9];
  const float* piq = (const float*)d_in[10];
  const float* pu  = (const float*)d_in[11];
  const float* po  = (const float*)d_in[12];
  const float* Wc  = (const float*)d_in[13];
  const float* bc  = (const float*)d_in[14];
  float* out = (float*)d_out;

  __bf16* W4p = (__bf16*)d_ws;                        // 6,291,456 bf16
  __bf16* Wcp = W4p + (size_t)256*48*64*8;            // 1,048,576 bf16
  __bf16* xF  = Wcp + (size_t)64*32*64*8;             // 8,388,608 bf16
  __bf16* actF = xF + (size_t)S_LEN*B_SZ*I_SZ;        // 262,144 bf16
  __bf16* hxF = actF + (size_t)4*B_SZ*H_SZ;           // 65,536 bf16
  float*  zact = (float*)(hxF + (size_t)B_SZ*H_SZ);   // 256 f32
  unsigned* flags = (unsigned*)(zact + 256);          // 256 u32

  pack_w4_k<<<256*48, 64, 0, stream>>>(Wf, Wi, Wu, Wo, W4p);
  pack_wc_k<<<64*32, 64, 0, stream>>>(Wc, Wcp);
  pack_x_k<<<S_LEN*4, 256, 0, stream>>>(inputs, xF);
  init_h_k<<<256, 256, 0, stream>>>(hxF);
  hipMemsetAsync(flags, 0, NBLK*sizeof(unsigned), stream);

  qlstm_persist_k<<<NBLK, 256, 0, stream>>>(
      xF, hxF, W4p, Wcp, bf_, bi_, bu_, bo_, pf, piq, pu, po,
      Wc + (size_t)H_SZ*H_SZ, bc, actF, zact, out, flags);
}